// Round 3
// baseline (913.568 us; speedup 1.0000x reference)
//
#include <hip/hip_runtime.h>

// Problem constants (fixed by reference setup_inputs)
#define BATCH 2
#define L_SEQ 768
#define NH 12
#define DH 64
#define ND 8
#define EMB 768
#define RSQRT8 0.35355339059327373f

// ws layout (floats). Total 6,046,480 floats = 24.2 MB -- UNCHANGED from the
// harness-verified baseline. Round-9 lesson: growing ws (kwT at 6,046,480+)
// is the prime suspect for the double container fault (OOB writes past the
// allocated workspace). kwT now ALIASES the dead 'part' region instead.
#define OFF_Q    0
#define OFF_K    1179648
#define OFF_V    2359296
#define OFF_L    3538944   // S0 per (bh,d,q): 147456
#define OFF_PART 3686400   // partial stats [bh*8+d][st*4+kq][q]: 2359296
                           //   dead after k3_reduce -> reused as kwT
                           //   [bh][64 dim][768 l] (1,179,648 <= 2,359,296)
#define OFF_P2   6045696   // per-(b,d,h) stat sums [bd][h][st]: 768
#define OFF_W    6046464   // weights [b][d]: 16

// ---------------------------------------------------------------------------
// K1: fused QKV projection. C = hs @ W + b, scattered to [b][h][l][64] layout.
// 64x64 tiles, 4x4 per thread, fp32 (no fp32 MFMA on CDNA4).
// ---------------------------------------------------------------------------
__global__ __launch_bounds__(256) void k1_qkv(
    const float* __restrict__ hs,
    const float* __restrict__ Wq, const float* __restrict__ bq,
    const float* __restrict__ Wk, const float* __restrict__ bk,
    const float* __restrict__ Wv, const float* __restrict__ bvp,
    float* __restrict__ qw, float* __restrict__ kw, float* __restrict__ vw)
{
    __shared__ float AsT[64][68];
    __shared__ float Bs[64][68];
    const int tid = threadIdx.x;
    const int tx = tid & 15, ty = tid >> 4;
    const int bx = blockIdx.x, by = blockIdx.y, gz = blockIdx.z;
    const float* W    = (gz == 0) ? Wq : (gz == 1 ? Wk : Wv);
    const float* bias = (gz == 0) ? bq : (gz == 1 ? bk : bvp);
    float* dst        = (gz == 0) ? qw : (gz == 1 ? kw : vw);

    const int ldc = tx * 4;

    float acc[4][4];
#pragma unroll
    for (int i = 0; i < 4; i++)
#pragma unroll
        for (int j = 0; j < 4; j++) acc[i][j] = 0.f;

    for (int k0 = 0; k0 < EMB; k0 += 64) {
        __syncthreads();
#pragma unroll
        for (int i = 0; i < 4; i++) {
            int r = ty + 16 * i;
            float4 a = *(const float4*)&hs[(size_t)(by * 64 + r) * EMB + k0 + ldc];
            AsT[ldc + 0][r] = a.x; AsT[ldc + 1][r] = a.y;
            AsT[ldc + 2][r] = a.z; AsT[ldc + 3][r] = a.w;
            *(float4*)&Bs[r][ldc] =
                *(const float4*)&W[(size_t)(k0 + r) * EMB + bx * 64 + ldc];
        }
        __syncthreads();
#pragma unroll 8
        for (int kk = 0; kk < 64; kk++) {
            float av[4], bb[4];
            *(float4*)av = *(const float4*)&AsT[kk][ty * 4];
            *(float4*)bb = *(const float4*)&Bs[kk][tx * 4];
#pragma unroll
            for (int i = 0; i < 4; i++)
#pragma unroll
                for (int j = 0; j < 4; j++)
                    acc[i][j] = fmaf(av[i], bb[j], acc[i][j]);
        }
    }

#pragma unroll
    for (int i = 0; i < 4; i++) {
        int m = by * 64 + ty * 4 + i;
        int b2 = m / L_SEQ, l = m % L_SEQ;
        float o[4];
#pragma unroll
        for (int j = 0; j < 4; j++) o[j] = acc[i][j] + bias[bx * 64 + tx * 4 + j];
        *(float4*)&dst[((size_t)(b2 * NH + bx) * L_SEQ + l) * DH + tx * 4] = *(float4*)o;
    }
}

// ---------------------------------------------------------------------------
// K2: softmax partial stats. Block = (bh, 64-q tile, k-quarter of 192).
// 4 waves x 16 q rows; lane = (qr, d); K chunk [64k][64dim] staged in LDS.
// ---------------------------------------------------------------------------
__global__ __launch_bounds__(256) void k2_stats(
    const float* __restrict__ qw, const float* __restrict__ kw,
    const float* __restrict__ mask, float* __restrict__ part)
{
    __shared__ float k_lds[64 * 64];
    __shared__ float m_lds[64];
    const int tid = threadIdx.x;
    const int lane = tid & 63, w = tid >> 6;
    const int qr = lane >> 3, d = lane & 7;
    const int blk = blockIdx.x;
    const int kq = blk & 3;
    const int t2 = blk >> 2;            // 0..287
    const int bh = t2 / 12;
    const int q0 = (t2 % 12) * 64;
    const int b = bh / NH;
    const int qw0 = q0 + w * 16;

    float qf[2][8];
#pragma unroll
    for (int qq = 0; qq < 2; qq++) {
        const float* qp = &qw[((size_t)bh * L_SEQ + qw0 + qr + qq * 8) * DH + d * 8];
        *(float4*)&qf[qq][0] = *(const float4*)qp;
        *(float4*)&qf[qq][4] = *(const float4*)(qp + 4);
    }
    float S[2] = {0.f, 0.f}, T2[2] = {0.f, 0.f}, SL[2] = {0.f, 0.f};
    float M[2] = {-1e30f, -1e30f};

    const int kb0 = kq * 192;
    for (int c = 0; c < 3; c++) {
        const int kb = kb0 + c * 64;
        __syncthreads();
        {
            const float* src = &kw[((size_t)bh * L_SEQ + kb) * DH];
#pragma unroll
            for (int i = 0; i < 4; i++) {
                int f = tid + 256 * i;
                *(float4*)&k_lds[f * 4] = *(const float4*)&src[f * 4];
            }
            if (tid < 64) m_lds[tid] = mask[b * L_SEQ + kb + tid];
        }
        __syncthreads();
#pragma unroll 4
        for (int kk = 0; kk < 64; kk++) {
            float kv[8];
            *(float4*)&kv[0] = *(const float4*)&k_lds[kk * 64 + d * 8];
            *(float4*)&kv[4] = *(const float4*)&k_lds[kk * 64 + d * 8 + 4];
            float mval = m_lds[kk];
#pragma unroll
            for (int qq = 0; qq < 2; qq++) {
                float s = 0.f;
#pragma unroll
                for (int t = 0; t < 8; t++) s = fmaf(qf[qq][t], kv[t], s);
                s = fmaf(s, RSQRT8, mval);
                float e = __expf(s);
                S[qq] += e;
                T2[qq] = fmaf(e, e, T2[qq]);
                SL[qq] = fmaf(s, e, SL[qq]);
                M[qq] = fmaxf(M[qq], s);
            }
        }
    }
#pragma unroll
    for (int qq = 0; qq < 2; qq++) {
        int q = qw0 + qr + qq * 8;
        size_t base = (size_t)(bh * 8 + d) * 16;
        part[(base + 0 + kq) * 768 + q] = S[qq];
        part[(base + 4 + kq) * 768 + q] = T2[qq];
        part[(base + 8 + kq) * 768 + q] = SL[qq];
        part[(base + 12 + kq) * 768 + q] = M[qq];
    }
}

// ---------------------------------------------------------------------------
// K3a: per-(b,d,h) combine of k-quarters -> row stats -> l_arr + stat sums.
// ---------------------------------------------------------------------------
__global__ __launch_bounds__(256) void k3_reduce(
    const float* __restrict__ part, float* __restrict__ l_arr,
    float* __restrict__ part2)
{
    const int bdh = blockIdx.x;         // ((b*8+d)*12+h)
    const int bd = bdh / 12, h = bdh % 12;
    const int b = bd >> 3, d = bd & 7;
    const int bh = b * NH + h;
    const int tid = threadIdx.x;
    const int lane = tid & 63, wave = tid >> 6;
    const size_t base = (size_t)(bh * 8 + d) * 16;
    float acc[4] = {0.f, 0.f, 0.f, 0.f};

    for (int q = tid; q < 768; q += 256) {
        float Sv = 0.f, T2v = 0.f, SLv = 0.f, Mv = -1e30f;
#pragma unroll
        for (int kq = 0; kq < 4; kq++) {
            Sv  += part[(base + 0 + kq) * 768 + q];
            T2v += part[(base + 4 + kq) * 768 + q];
            SLv += part[(base + 8 + kq) * 768 + q];
            Mv = fmaxf(Mv, part[(base + 12 + kq) * 768 + q]);
        }
        l_arr[(size_t)(bh * 8 + d) * 768 + q] = Sv;
        float inv = 1.0f / Sv;
        float hhi = T2v * inv * inv;
        float maxp = __expf(Mv) * inv;
        float ent = __logf(Sv) - SLv * inv;
        float var = (hhi - (1.0f / 768.0f)) * (1.0f / 767.0f);
        acc[0] += var; acc[1] += maxp; acc[2] += ent; acc[3] += hhi;
    }
    __shared__ float red[4][4];
#pragma unroll
    for (int st = 0; st < 4; st++) {
        float a = acc[st];
#pragma unroll
        for (int off = 32; off > 0; off >>= 1) a += __shfl_xor(a, off, 64);
        acc[st] = a;
    }
    if (lane == 0) {
#pragma unroll
        for (int st = 0; st < 4; st++) red[wave][st] = acc[st];
    }
    __syncthreads();
    if (tid == 0) {
#pragma unroll
        for (int st = 0; st < 4; st++)
            part2[(size_t)(bd * 12 + h) * 4 + st] =
                red[0][st] + red[1][st] + red[2][st] + red[3][st];
    }
}

// ---------------------------------------------------------------------------
// K3b: sum over h, min-max norm over d, softmax(2.5*score) -> weights[b][d].
// ---------------------------------------------------------------------------
__global__ __launch_bounds__(64) void k3_weights(
    const float* __restrict__ part2, float* __restrict__ wgt)
{
    __shared__ float stats_l[64];       // [b][d][st]
    const int tid = threadIdx.x;
    {
        const int bd = tid >> 2, st = tid & 3;
        float s = 0.f;
#pragma unroll
        for (int h = 0; h < 12; h++) s += part2[(size_t)(bd * 12 + h) * 4 + st];
        stats_l[tid] = s * (1.0f / 9216.0f);
    }
    __syncthreads();
    if (tid == 0) {
        for (int b = 0; b < BATCH; b++) {
            float v[4][8];
            for (int st = 0; st < 4; st++)
                for (int d = 0; d < 8; d++) v[st][d] = stats_l[(b * 8 + d) * 4 + st];
            float nrm[4][8];
            for (int st = 0; st < 4; st++) {
                float mn = v[st][0], mx = v[st][0];
                for (int d = 1; d < 8; d++) { mn = fminf(mn, v[st][d]); mx = fmaxf(mx, v[st][d]); }
                float rng = fmaxf(mx - mn, 1e-12f);
                for (int d = 0; d < 8; d++) nrm[st][d] = (v[st][d] - mn) / rng;
            }
            float sc[8];
            for (int d = 0; d < 8; d++)
                sc[d] = 0.5f * nrm[0][d] + 0.3f * nrm[1][d] + 0.2f * nrm[3][d] - 0.4f * nrm[2][d];
            float m = 2.5f * sc[0];
            for (int d = 1; d < 8; d++) m = fmaxf(m, 2.5f * sc[d]);
            float e8[8]; float ssum = 0.f;
            for (int d = 0; d < 8; d++) { e8[d] = __expf(2.5f * sc[d] - m); ssum += e8[d]; }
            for (int d = 0; d < 8; d++) wgt[b * ND + d] = e8[d] / ssum;
        }
    }
}

// ---------------------------------------------------------------------------
// KT: tile-transpose kw[bh][l][dim] -> kwT[bh][dim][l] (into dead 'part').
// 64x64 tiles via LDS; both global sides coalesced float4. Runs AFTER
// k3_reduce (part dead) and BEFORE k45. ~9.4 MB traffic ~= 1-2 us.
// ---------------------------------------------------------------------------
__global__ __launch_bounds__(256) void kT_transpose(
    const float* __restrict__ kw, float* __restrict__ kwT)
{
    __shared__ float t[64][68];
    const int tid = threadIdx.x;
    const int bh = blockIdx.x / 12;
    const int l0 = (blockIdx.x % 12) * 64;
    const float* src = &kw[((size_t)bh * L_SEQ + l0) * DH];
#pragma unroll
    for (int i = 0; i < 4; i++) {
        int f = tid + 256 * i;
        int row = f >> 4, col = (f & 15) * 4;
        *(float4*)&t[row][col] = *(const float4*)&src[(size_t)row * DH + col];
    }
    __syncthreads();
    float* dst = &kwT[(size_t)bh * DH * L_SEQ + l0];
#pragma unroll
    for (int i = 0; i < 4; i++) {
        int f = tid + 256 * i;
        int dim = f >> 4, l4 = (f & 15) * 4;
        float4 o = {t[l4 + 0][dim], t[l4 + 1][dim], t[l4 + 2][dim], t[l4 + 3][dim]};
        *(float4*)&dst[(size_t)dim * L_SEQ + l4] = o;
    }
}

// ---------------------------------------------------------------------------
// K45 v3 (round-10): register-blocked a4+ctx, DS pipe nearly empty, FULL k
// per block (no partials, no extra ws).
// ROUND-8 LESSON (rocprof arithmetic): v1 was LDS-READ-PIPE bound: 6.2M
// ds_read_b128 x 12cy / 256 CU = 118us ~= measured 121us, while pure FMA is
// only ~28us (VALUBusy 44%, HBM 10%).
// FIX: 4qx4k register tile per lane (lane = qg(2) x kl(32)); per d-slice read
// 8 q-frags (row-major qw, broadcast) + 8 k-frags (transposed kwT, 512B
// contiguous) from GLOBAL/L1 (VMEM pipe, not DS) -> 128 FMA. Phase B reads V
// per-k from global (chunk L1/L2-resident). LDS holds ONLY the wave-private
// a4 k->q transpose [8q][132k]: 8 b128 writes + 64 broadcast b128 reads per
// wave-chunk (~0.8Kcy, 6x under the ~5Kcy VALU). No __syncthreads at all.
// Block = (bh, 32-q tile), grid 576, 4 waves x 8 q rows, 6 chunks x 128 k.
// a4 per-element fmaf/exp order identical to round-1 -> absmax unchanged.
// ---------------------------------------------------------------------------
__global__ __launch_bounds__(256) void k45_fused(
    const float* __restrict__ qw, const float* __restrict__ kwT,
    const float* __restrict__ vw, const float* __restrict__ mask,
    const float* __restrict__ l_arr, const float* __restrict__ wgt,
    float* __restrict__ out_a4, float* __restrict__ out_ctx)
{
    __shared__ float a4T[4][8][132];        // per-wave [q][k], pad 132
    const int tid = threadIdx.x;
    const int lane = tid & 63, w = tid >> 6;
    const int qg = lane >> 5;               // 0..1  -> q rows qbase..qbase+3
    const int kl = lane & 31;               // 0..31 -> k cols kl*4..+3 per chunk
    const int blk = blockIdx.x;
    const int bh = blk / 24;                // 0..23
    const int q0 = (blk % 24) * 32;
    const int b = bh / NH, h = bh % NH;
    const int qw0 = q0 + w * 8;             // wave owns 8 q rows
    const int qbase = qw0 + qg * 4;

    // phase B lane mapping: rows (rb, rb+4) of the wave's 8, dh cols cb*4..+3
    const int rb = lane >> 4;               // 0..3
    const int cb = lane & 15;               // 0..15

    // c0[d][i] = w_d / l(bh,d,row_i): same ops as round-1.
    float c0[8][4];
#pragma unroll
    for (int d = 0; d < 8; d++) {
        float4 lv = *(const float4*)&l_arr[(size_t)(bh * 8 + d) * L_SEQ + qbase];
        float wd = wgt[b * ND + d];
        c0[d][0] = wd / lv.x; c0[d][1] = wd / lv.y;
        c0[d][2] = wd / lv.z; c0[d][3] = wd / lv.w;
    }

    const float* qrow0 = &qw[(size_t)bh * L_SEQ * DH];
    const float* kT    = &kwT[(size_t)bh * DH * L_SEQ];

    float accL[4], accH[4];                 // ctx rows rb / rb+4
#pragma unroll
    for (int j = 0; j < 4; j++) { accL[j] = 0.f; accH[j] = 0.f; }

    for (int c = 0; c < 6; c++) {
        const int kb = c * 128;
        const int kcol = kb + kl * 4;
        float4 mv4 = *(const float4*)&mask[b * L_SEQ + kcol];
        float mv[4] = {mv4.x, mv4.y, mv4.z, mv4.w};

        float a4[4][4];
#pragma unroll
        for (int i = 0; i < 4; i++)
#pragma unroll
            for (int j = 0; j < 4; j++) a4[i][j] = 0.f;

#pragma unroll
        for (int d = 0; d < 8; d++) {
            // q frags: 4 rows x 8 floats (broadcast across the 32 kl lanes)
            float qv[4][8];
#pragma unroll
            for (int i = 0; i < 4; i++) {
                const float* qp = &qrow0[(size_t)(qbase + i) * DH + d * 8];
                *(float4*)&qv[i][0] = *(const float4*)qp;
                *(float4*)&qv[i][4] = *(const float4*)(qp + 4);
            }
            float s[4][4];
#pragma unroll
            for (int i = 0; i < 4; i++)
#pragma unroll
                for (int j = 0; j < 4; j++) s[i][j] = 0.f;
            // k frags from kwT: per dim one 512B-contiguous b128 read
#pragma unroll
            for (int t = 0; t < 8; t++) {
                float4 kf = *(const float4*)&kT[(size_t)(d * 8 + t) * L_SEQ + kcol];
                float ka[4] = {kf.x, kf.y, kf.z, kf.w};
#pragma unroll
                for (int i = 0; i < 4; i++)
#pragma unroll
                    for (int j = 0; j < 4; j++)
                        s[i][j] = fmaf(qv[i][t], ka[j], s[i][j]);
            }
#pragma unroll
            for (int i = 0; i < 4; i++)
#pragma unroll
                for (int j = 0; j < 4; j++) {
                    float sv = fmaf(s[i][j], RSQRT8, mv[j]);
                    a4[i][j] = fmaf(c0[d][i], __expf(sv), a4[i][j]);
                }
        }

        // a4 -> global straight from registers (lanes kl contiguous per row)
#pragma unroll
        for (int i = 0; i < 4; i++) {
            float4 o = {a4[i][0], a4[i][1], a4[i][2], a4[i][3]};
            *(float4*)&out_a4[((size_t)bh * L_SEQ + qbase + i) * L_SEQ + kcol] = o;
        }
        // a4 -> wave-private LDS [q][k] (no barrier: same-wave lgkmcnt dep)
#pragma unroll
        for (int i = 0; i < 4; i++) {
            float4 o = {a4[i][0], a4[i][1], a4[i][2], a4[i][3]};
            *(float4*)&a4T[w][qg * 4 + i][kl * 4] = o;
        }

        // Phase B: ctx += a4 @ V over this 128-k chunk (k ascending).
        // a4T reads: 16-lane broadcast, rows rb/rb+4 -> disjoint bank groups.
        const float* vb = &vw[((size_t)bh * L_SEQ + kb) * DH + cb * 4];
#pragma unroll 8
        for (int kg = 0; kg < 32; kg++) {
            float aL[4], aH[4];
            *(float4*)aL = *(const float4*)&a4T[w][rb][kg * 4];
            *(float4*)aH = *(const float4*)&a4T[w][rb + 4][kg * 4];
#pragma unroll
            for (int u = 0; u < 4; u++) {
                float4 vv = *(const float4*)&vb[(size_t)(kg * 4 + u) * DH];
                accL[0] = fmaf(aL[u], vv.x, accL[0]);
                accL[1] = fmaf(aL[u], vv.y, accL[1]);
                accL[2] = fmaf(aL[u], vv.z, accL[2]);
                accL[3] = fmaf(aL[u], vv.w, accL[3]);
                accH[0] = fmaf(aH[u], vv.x, accH[0]);
                accH[1] = fmaf(aH[u], vv.y, accH[1]);
                accH[2] = fmaf(aH[u], vv.z, accH[2]);
                accH[3] = fmaf(aH[u], vv.w, accH[3]);
            }
        }
    }

    // ctx store: rows (qw0+rb, qw0+rb+4), dh cols cb*4..+3 -- full k done.
    {
        float4 oL = {accL[0], accL[1], accL[2], accL[3]};
        float4 oH = {accH[0], accH[1], accH[2], accH[3]};
        *(float4*)&out_ctx[((size_t)b * L_SEQ + qw0 + rb) * EMB + h * DH + cb * 4] = oL;
        *(float4*)&out_ctx[((size_t)b * L_SEQ + qw0 + rb + 4) * EMB + h * DH + cb * 4] = oH;
    }
}

// ---------------------------------------------------------------------------
extern "C" void kernel_launch(void* const* d_in, const int* in_sizes, int n_in,
                              void* d_out, int out_size, void* d_ws, size_t ws_size,
                              hipStream_t stream)
{
    const float* hs   = (const float*)d_in[0];
    const float* mask = (const float*)d_in[1];
    const float* Wq   = (const float*)d_in[2];
    const float* bq   = (const float*)d_in[3];
    const float* Wk   = (const float*)d_in[4];
    const float* bk   = (const float*)d_in[5];
    const float* Wv   = (const float*)d_in[6];
    const float* bv   = (const float*)d_in[7];

    float* ws = (float*)d_ws;
    float* qw    = ws + OFF_Q;
    float* kw    = ws + OFF_K;
    float* vw    = ws + OFF_V;
    float* l_arr = ws + OFF_L;
    float* part  = ws + OFF_PART;   // after k3_reduce: reused as kwT
    float* part2 = ws + OFF_P2;
    float* wgt   = ws + OFF_W;
    float* kwT   = part;            // [24 bh][64 dim][768 l]

    float* out_ctx = (float*)d_out;                                  // [B, L, 768]
    float* out_a4  = (float*)d_out + (size_t)BATCH * L_SEQ * EMB;    // [B, H, L, L]

    k1_qkv<<<dim3(12, 24, 3), 256, 0, stream>>>(hs, Wq, bq, Wk, bk, Wv, bv, qw, kw, vw);
    k2_stats<<<dim3(1152), 256, 0, stream>>>(qw, kw, mask, part);
    k3_reduce<<<dim3(192), 256, 0, stream>>>(part, l_arr, part2);
    k3_weights<<<dim3(1), 64, 0, stream>>>(part2, wgt);
    kT_transpose<<<dim3(288), 256, 0, stream>>>(kw, kwT);
    k45_fused<<<dim3(576), 256, 0, stream>>>(qw, kwT, vw, mask, l_arr, wgt,
                                             out_a4, out_ctx);
}

// Round 4
// 375.258 us; speedup vs baseline: 2.4345x; 2.4345x over previous
//
#include <hip/hip_runtime.h>

// Problem constants (fixed by reference setup_inputs)
#define BATCH 2
#define L_SEQ 768
#define NH 12
#define DH 64
#define ND 8
#define EMB 768
#define RSQRT8 0.35355339059327373f

// ws layout (floats). Total 6,046,480 floats = 24.2 MB -- UNCHANGED footprint.
#define OFF_Q    0
#define OFF_K    1179648
#define OFF_V    2359296
#define OFF_L    3538944   // linv[bh][q][d] = 1/S : 147456
#define OFF_PART 3686400   // partial stats [bh*8+d][st*4+kq][q]: 2359296
#define OFF_P2   6045696   // per-(b,d,h) stat sums [bd][h][st]: 768
#define OFF_W    6046464   // weights [b][d]: 16

// ---------------------------------------------------------------------------
// K1: fused QKV projection. C = hs @ W + b, scattered to [b][h][l][64] layout.
// 64x64 tiles, 4x4 per thread, fp32 (no fp32 MFMA on CDNA4).
// ---------------------------------------------------------------------------
__global__ __launch_bounds__(256) void k1_qkv(
    const float* __restrict__ hs,
    const float* __restrict__ Wq, const float* __restrict__ bq,
    const float* __restrict__ Wk, const float* __restrict__ bk,
    const float* __restrict__ Wv, const float* __restrict__ bvp,
    float* __restrict__ qw, float* __restrict__ kw, float* __restrict__ vw)
{
    __shared__ float AsT[64][68];
    __shared__ float Bs[64][68];
    const int tid = threadIdx.x;
    const int tx = tid & 15, ty = tid >> 4;
    const int bx = blockIdx.x, by = blockIdx.y, gz = blockIdx.z;
    const float* W    = (gz == 0) ? Wq : (gz == 1 ? Wk : Wv);
    const float* bias = (gz == 0) ? bq : (gz == 1 ? bk : bvp);
    float* dst        = (gz == 0) ? qw : (gz == 1 ? kw : vw);

    const int ldc = tx * 4;

    float acc[4][4];
#pragma unroll
    for (int i = 0; i < 4; i++)
#pragma unroll
        for (int j = 0; j < 4; j++) acc[i][j] = 0.f;

    for (int k0 = 0; k0 < EMB; k0 += 64) {
        __syncthreads();
#pragma unroll
        for (int i = 0; i < 4; i++) {
            int r = ty + 16 * i;
            float4 a = *(const float4*)&hs[(size_t)(by * 64 + r) * EMB + k0 + ldc];
            AsT[ldc + 0][r] = a.x; AsT[ldc + 1][r] = a.y;
            AsT[ldc + 2][r] = a.z; AsT[ldc + 3][r] = a.w;
            *(float4*)&Bs[r][ldc] =
                *(const float4*)&W[(size_t)(k0 + r) * EMB + bx * 64 + ldc];
        }
        __syncthreads();
#pragma unroll 8
        for (int kk = 0; kk < 64; kk++) {
            float av[4], bb[4];
            *(float4*)av = *(const float4*)&AsT[kk][ty * 4];
            *(float4*)bb = *(const float4*)&Bs[kk][tx * 4];
#pragma unroll
            for (int i = 0; i < 4; i++)
#pragma unroll
                for (int j = 0; j < 4; j++)
                    acc[i][j] = fmaf(av[i], bb[j], acc[i][j]);
        }
    }

#pragma unroll
    for (int i = 0; i < 4; i++) {
        int m = by * 64 + ty * 4 + i;
        int b2 = m / L_SEQ, l = m % L_SEQ;
        float o[4];
#pragma unroll
        for (int j = 0; j < 4; j++) o[j] = acc[i][j] + bias[bx * 64 + tx * 4 + j];
        *(float4*)&dst[((size_t)(b2 * NH + bx) * L_SEQ + l) * DH + tx * 4] = *(float4*)o;
    }
}

// ---------------------------------------------------------------------------
// K2: softmax partial stats. Block = (bh, 64-q tile, k-quarter of 192).
// 4 waves x 16 q rows; lane = (qr, d); K chunk [64k][64dim] staged in LDS.
// ---------------------------------------------------------------------------
__global__ __launch_bounds__(256) void k2_stats(
    const float* __restrict__ qw, const float* __restrict__ kw,
    const float* __restrict__ mask, float* __restrict__ part)
{
    __shared__ float k_lds[64 * 64];
    __shared__ float m_lds[64];
    const int tid = threadIdx.x;
    const int lane = tid & 63, w = tid >> 6;
    const int qr = lane >> 3, d = lane & 7;
    const int blk = blockIdx.x;
    const int kq = blk & 3;
    const int t2 = blk >> 2;            // 0..287
    const int bh = t2 / 12;
    const int q0 = (t2 % 12) * 64;
    const int b = bh / NH;
    const int qw0 = q0 + w * 16;

    float qf[2][8];
#pragma unroll
    for (int qq = 0; qq < 2; qq++) {
        const float* qp = &qw[((size_t)bh * L_SEQ + qw0 + qr + qq * 8) * DH + d * 8];
        *(float4*)&qf[qq][0] = *(const float4*)qp;
        *(float4*)&qf[qq][4] = *(const float4*)(qp + 4);
    }
    float S[2] = {0.f, 0.f}, T2[2] = {0.f, 0.f}, SL[2] = {0.f, 0.f};
    float M[2] = {-1e30f, -1e30f};

    const int kb0 = kq * 192;
    for (int c = 0; c < 3; c++) {
        const int kb = kb0 + c * 64;
        __syncthreads();
        {
            const float* src = &kw[((size_t)bh * L_SEQ + kb) * DH];
#pragma unroll
            for (int i = 0; i < 4; i++) {
                int f = tid + 256 * i;
                *(float4*)&k_lds[f * 4] = *(const float4*)&src[f * 4];
            }
            if (tid < 64) m_lds[tid] = mask[b * L_SEQ + kb + tid];
        }
        __syncthreads();
#pragma unroll 4
        for (int kk = 0; kk < 64; kk++) {
            float kv[8];
            *(float4*)&kv[0] = *(const float4*)&k_lds[kk * 64 + d * 8];
            *(float4*)&kv[4] = *(const float4*)&k_lds[kk * 64 + d * 8 + 4];
            float mval = m_lds[kk];
#pragma unroll
            for (int qq = 0; qq < 2; qq++) {
                float s = 0.f;
#pragma unroll
                for (int t = 0; t < 8; t++) s = fmaf(qf[qq][t], kv[t], s);
                s = fmaf(s, RSQRT8, mval);
                float e = __expf(s);
                S[qq] += e;
                T2[qq] = fmaf(e, e, T2[qq]);
                SL[qq] = fmaf(s, e, SL[qq]);
                M[qq] = fmaxf(M[qq], s);
            }
        }
    }
#pragma unroll
    for (int qq = 0; qq < 2; qq++) {
        int q = qw0 + qr + qq * 8;
        size_t base = (size_t)(bh * 8 + d) * 16;
        part[(base + 0 + kq) * 768 + q] = S[qq];
        part[(base + 4 + kq) * 768 + q] = T2[qq];
        part[(base + 8 + kq) * 768 + q] = SL[qq];
        part[(base + 12 + kq) * 768 + q] = M[qq];
    }
}

// ---------------------------------------------------------------------------
// K3a: per-(b,d,h) combine of k-quarters -> row stats -> linv + stat sums.
// Round-11 change: store 1/S (not S) in [bh][q][d] layout so k45 can fetch
// all 8 d-values for a q row with one uniform (scalar) 8-float load.
// ---------------------------------------------------------------------------
__global__ __launch_bounds__(256) void k3_reduce(
    const float* __restrict__ part, float* __restrict__ linv,
    float* __restrict__ part2)
{
    const int bdh = blockIdx.x;         // ((b*8+d)*12+h)
    const int bd = bdh / 12, h = bdh % 12;
    const int b = bd >> 3, d = bd & 7;
    const int bh = b * NH + h;
    const int tid = threadIdx.x;
    const int lane = tid & 63, wave = tid >> 6;
    const size_t base = (size_t)(bh * 8 + d) * 16;
    float acc[4] = {0.f, 0.f, 0.f, 0.f};

    for (int q = tid; q < 768; q += 256) {
        float Sv = 0.f, T2v = 0.f, SLv = 0.f, Mv = -1e30f;
#pragma unroll
        for (int kq = 0; kq < 4; kq++) {
            Sv  += part[(base + 0 + kq) * 768 + q];
            T2v += part[(base + 4 + kq) * 768 + q];
            SLv += part[(base + 8 + kq) * 768 + q];
            Mv = fmaxf(Mv, part[(base + 12 + kq) * 768 + q]);
        }
        float inv = 1.0f / Sv;
        linv[((size_t)bh * 768 + q) * 8 + d] = inv;
        float hhi = T2v * inv * inv;
        float maxp = __expf(Mv) * inv;
        float ent = __logf(Sv) - SLv * inv;
        float var = (hhi - (1.0f / 768.0f)) * (1.0f / 767.0f);
        acc[0] += var; acc[1] += maxp; acc[2] += ent; acc[3] += hhi;
    }
    __shared__ float red[4][4];
#pragma unroll
    for (int st = 0; st < 4; st++) {
        float a = acc[st];
#pragma unroll
        for (int off = 32; off > 0; off >>= 1) a += __shfl_xor(a, off, 64);
        acc[st] = a;
    }
    if (lane == 0) {
#pragma unroll
        for (int st = 0; st < 4; st++) red[wave][st] = acc[st];
    }
    __syncthreads();
    if (tid == 0) {
#pragma unroll
        for (int st = 0; st < 4; st++)
            part2[(size_t)(bd * 12 + h) * 4 + st] =
                red[0][st] + red[1][st] + red[2][st] + red[3][st];
    }
}

// ---------------------------------------------------------------------------
// K3b: sum over h, min-max norm over d, softmax(2.5*score) -> weights[b][d].
// ---------------------------------------------------------------------------
__global__ __launch_bounds__(64) void k3_weights(
    const float* __restrict__ part2, float* __restrict__ wgt)
{
    __shared__ float stats_l[64];       // [b][d][st]
    const int tid = threadIdx.x;
    {
        const int bd = tid >> 2, st = tid & 3;
        float s = 0.f;
#pragma unroll
        for (int h = 0; h < 12; h++) s += part2[(size_t)(bd * 12 + h) * 4 + st];
        stats_l[tid] = s * (1.0f / 9216.0f);
    }
    __syncthreads();
    if (tid == 0) {
        for (int b = 0; b < BATCH; b++) {
            float v[4][8];
            for (int st = 0; st < 4; st++)
                for (int d = 0; d < 8; d++) v[st][d] = stats_l[(b * 8 + d) * 4 + st];
            float nrm[4][8];
            for (int st = 0; st < 4; st++) {
                float mn = v[st][0], mx = v[st][0];
                for (int d = 1; d < 8; d++) { mn = fminf(mn, v[st][d]); mx = fmaxf(mx, v[st][d]); }
                float rng = fmaxf(mx - mn, 1e-12f);
                for (int d = 0; d < 8; d++) nrm[st][d] = (v[st][d] - mn) / rng;
            }
            float sc[8];
            for (int d = 0; d < 8; d++)
                sc[d] = 0.5f * nrm[0][d] + 0.3f * nrm[1][d] + 0.2f * nrm[3][d] - 0.4f * nrm[2][d];
            float m = 2.5f * sc[0];
            for (int d = 1; d < 8; d++) m = fmaxf(m, 2.5f * sc[d]);
            float e8[8]; float ssum = 0.f;
            for (int d = 0; d < 8; d++) { e8[d] = __expf(2.5f * sc[d] - m); ssum += e8[d]; }
            for (int d = 0; d < 8; d++) wgt[b * ND + d] = e8[d] / ssum;
        }
    }
}

// ---------------------------------------------------------------------------
// K45 v4 (round-11): pipe-split a4+ctx.
// ROUND-10 LESSON (rocprof): v3 (all-VMEM fragments) = latency wall: VGPR 240
// -> 2.8 waves/CU, VALUBusy 8.5%, 688us. ROUND-8 LESSON: all-LDS streaming =
// DS-pipe instr bound (12cy/b128/CU), 121us floor.
// FIX: split operands across pipes.
//   Q -> SCALAR pipe: q addresses are block-uniform -> s_load; dot FMAs are
//        v_fma(sgpr,vgpr). Zero DS/VMEM-vector/VGPR cost for Q.
//   K -> VGPRs: lane = k. Each lane owns one K row (64 VGPR), 16 coalesced
//        b128 VMEM loads per 64-k chunk (v1-proven pattern).
//   a4 -> LDS only for the k->q transpose: 8 b128 writes + 192 b128 reads
//        per wave-chunk (~2.6Kcy/CU-chunk, under the ~12Kcy VALU).
//   V -> VMEM per-k b128 (L2-resident chunk), broadcast 4-wide.
// Waves partition k (wave w owns chunks 3w..3w+2) over SHARED 32 q rows;
// ctx partials block-reduced once via LDS at the end (single barrier).
// Per-element math identical to round-1 except c0 = wgt*(1/l) (<=2ulp).
// Block = (bh, 32-q tile), grid 576, LDS 36.9 KB, VGPR ~140.
// ---------------------------------------------------------------------------
__global__ __launch_bounds__(256, 2) void k45_fused(
    const float* __restrict__ qw, const float* __restrict__ kw,
    const float* __restrict__ vw, const float* __restrict__ mask,
    const float* __restrict__ linv, const float* __restrict__ wgt,
    float* __restrict__ out_a4, float* __restrict__ out_ctx)
{
    // per-wave region: a4T [k 64][36 pad] during chunks; ctx [q 32][68 pad] at end
    __shared__ float smem[4][64 * 36];
    const int tid = threadIdx.x;
    const int lane = tid & 63, w = tid >> 6;
    const int blk = blockIdx.x;
    const int bh = blk / 24;                // 0..23
    const int q0 = (blk % 24) * 32;
    const int b = bh / NH, h = bh % NH;
    // phase-B lane mapping: 8 q rows (qg*8..+7) x 4 dh cols (dhl*4..+3)
    const int qg = lane >> 4;               // 0..3
    const int dhl = lane & 15;              // 0..15

    const float* kbase = &kw[(size_t)bh * L_SEQ * DH];
    const float* vbase = &vw[(size_t)bh * L_SEQ * DH];
    const float* qtile = &qw[((size_t)bh * L_SEQ + q0) * DH];   // block-uniform rows
    const float* ltile = &linv[((size_t)bh * L_SEQ + q0) * 8];

    // wgt[b][0..7]: uniform -> SGPRs
    float wv[8];
#pragma unroll
    for (int d = 0; d < 8; d++) wv[d] = wgt[b * ND + d];

    float acc[8][4];                        // ctx partial: 8 q rows x 4 dh
#pragma unroll
    for (int i = 0; i < 8; i++)
#pragma unroll
        for (int j = 0; j < 4; j++) acc[i][j] = 0.f;

    float* sm = &smem[w][0];

    for (int c = 0; c < 3; c++) {
        const int kb = (w * 3 + c) * 64;    // this wave's k chunk
        const int krow = kb + lane;

        // K row -> VGPRs (coalesced: lanes hit consecutive 256B rows)
        float kv[64];
        {
            const float* kp = &kbase[(size_t)krow * DH];
#pragma unroll
            for (int t = 0; t < 16; t++)
                *(float4*)&kv[t * 4] = *(const float4*)&kp[t * 4];
        }
        const float mval = mask[b * L_SEQ + krow];

        // ---- Phase A: a4(q, krow) for 32 q rows, Q via scalar loads ----
        for (int q4 = 0; q4 < 8; q4++) {
            float a4q[4];
#pragma unroll
            for (int u = 0; u < 4; u++) {
                const int q = q4 * 4 + u;
                const float* qp = &qtile[(size_t)q * DH];
                const float* lp = &ltile[(size_t)q * 8];
                // 8 independent dot chains, t ascending per d (round-1 order)
                float sd[8];
#pragma unroll
                for (int d = 0; d < 8; d++) sd[d] = 0.f;
#pragma unroll
                for (int d = 0; d < 8; d++)
#pragma unroll
                    for (int t = 0; t < 8; t++)
                        sd[d] = fmaf(qp[d * 8 + t], kv[d * 8 + t], sd[d]);
                float c0[8];
#pragma unroll
                for (int d = 0; d < 8; d++) c0[d] = wv[d] * lp[d];
                float a4v = 0.f;
#pragma unroll
                for (int d = 0; d < 8; d++) {
                    float sv = fmaf(sd[d], RSQRT8, mval);
                    a4v = fmaf(c0[d], __expf(sv), a4v);
                }
                out_a4[((size_t)bh * L_SEQ + q0 + q) * L_SEQ + krow] = a4v;
                a4q[u] = a4v;
            }
            // a4T[k][q4*4..+3] (wave-private; same-wave lgkmcnt ordering)
            *(float4*)&sm[lane * 36 + q4 * 4] = *(float4*)a4q;
        }

        // ---- Phase B: ctx += a4T @ V over this chunk (k ascending) ----
        const float* vrow = &vbase[(size_t)kb * DH + dhl * 4];
#pragma unroll 8
        for (int k = 0; k < 64; k++) {
            float aA[4], aB[4];
            *(float4*)aA = *(const float4*)&sm[k * 36 + qg * 8];
            *(float4*)aB = *(const float4*)&sm[k * 36 + qg * 8 + 4];
            float4 vv = *(const float4*)&vrow[(size_t)k * DH];
#pragma unroll
            for (int i = 0; i < 4; i++) {
                acc[i][0] = fmaf(aA[i], vv.x, acc[i][0]);
                acc[i][1] = fmaf(aA[i], vv.y, acc[i][1]);
                acc[i][2] = fmaf(aA[i], vv.z, acc[i][2]);
                acc[i][3] = fmaf(aA[i], vv.w, acc[i][3]);
                acc[i + 4][0] = fmaf(aB[i], vv.x, acc[i + 4][0]);
                acc[i + 4][1] = fmaf(aB[i], vv.y, acc[i + 4][1]);
                acc[i + 4][2] = fmaf(aB[i], vv.z, acc[i + 4][2]);
                acc[i + 4][3] = fmaf(aB[i], vv.w, acc[i + 4][3]);
            }
        }
    }

    // ---- ctx k-partials -> LDS (alias a4T region), block-reduce over waves ----
#pragma unroll
    for (int i = 0; i < 8; i++)
        *(float4*)&sm[(qg * 8 + i) * 68 + dhl * 4] = *(float4*)&acc[i][0];
    __syncthreads();
    {
        const int q = tid >> 3;             // 0..31
        const int dh8 = (tid & 7) * 8;      // 0..56
        float r[8];
#pragma unroll
        for (int j = 0; j < 8; j++) r[j] = 0.f;
#pragma unroll
        for (int ww = 0; ww < 4; ww++) {
            const float* s2 = &smem[ww][q * 68 + dh8];
#pragma unroll
            for (int j = 0; j < 8; j++) r[j] += s2[j];
        }
        float* op = &out_ctx[((size_t)b * L_SEQ + q0 + q) * EMB + h * DH + dh8];
        *(float4*)&op[0] = *(float4*)&r[0];
        *(float4*)&op[4] = *(float4*)&r[4];
    }
}

// ---------------------------------------------------------------------------
extern "C" void kernel_launch(void* const* d_in, const int* in_sizes, int n_in,
                              void* d_out, int out_size, void* d_ws, size_t ws_size,
                              hipStream_t stream)
{
    const float* hs   = (const float*)d_in[0];
    const float* mask = (const float*)d_in[1];
    const float* Wq   = (const float*)d_in[2];
    const float* bq   = (const float*)d_in[3];
    const float* Wk   = (const float*)d_in[4];
    const float* bk   = (const float*)d_in[5];
    const float* Wv   = (const float*)d_in[6];
    const float* bv   = (const float*)d_in[7];

    float* ws = (float*)d_ws;
    float* qw    = ws + OFF_Q;
    float* kw    = ws + OFF_K;
    float* vw    = ws + OFF_V;
    float* linv  = ws + OFF_L;
    float* part  = ws + OFF_PART;
    float* part2 = ws + OFF_P2;
    float* wgt   = ws + OFF_W;

    float* out_ctx = (float*)d_out;                                  // [B, L, 768]
    float* out_a4  = (float*)d_out + (size_t)BATCH * L_SEQ * EMB;    // [B, H, L, L]

    k1_qkv<<<dim3(12, 24, 3), 256, 0, stream>>>(hs, Wq, bq, Wk, bk, Wv, bv, qw, kw, vw);
    k2_stats<<<dim3(1152), 256, 0, stream>>>(qw, kw, mask, part);
    k3_reduce<<<dim3(192), 256, 0, stream>>>(part, linv, part2);
    k3_weights<<<dim3(1), 64, 0, stream>>>(part2, wgt);
    k45_fused<<<dim3(576), 256, 0, stream>>>(qw, kw, vw, mask, linv, wgt,
                                             out_a4, out_ctx);
}

// Round 5
// 330.439 us; speedup vs baseline: 2.7647x; 1.1356x over previous
//
#include <hip/hip_runtime.h>

// Problem constants (fixed by reference setup_inputs)
#define BATCH 2
#define L_SEQ 768
#define NH 12
#define DH 64
#define ND 8
#define EMB 768
#define RSQRT8 0.35355339059327373f

// ws layout (floats). Total 6,046,480 floats = 24.2 MB -- UNCHANGED footprint.
#define OFF_Q    0
#define OFF_K    1179648
#define OFF_V    2359296
#define OFF_L    3538944   // linv[bh][q][d] = 1/S : 147456
#define OFF_PART 3686400   // partial stats [bh*8+d][st*4+kq][q]: 2359296
#define OFF_P2   6045696   // per-(b,d,h) stat sums [bd][h][st]: 768
#define OFF_W    6046464   // weights [b][d]: 16

// ---------------------------------------------------------------------------
// K1: fused QKV projection. C = hs @ W + b, scattered to [b][h][l][64] layout.
// 64x64 tiles, 4x4 per thread, fp32 (no fp32 MFMA on CDNA4).
// ---------------------------------------------------------------------------
__global__ __launch_bounds__(256) void k1_qkv(
    const float* __restrict__ hs,
    const float* __restrict__ Wq, const float* __restrict__ bq,
    const float* __restrict__ Wk, const float* __restrict__ bk,
    const float* __restrict__ Wv, const float* __restrict__ bvp,
    float* __restrict__ qw, float* __restrict__ kw, float* __restrict__ vw)
{
    __shared__ float AsT[64][68];
    __shared__ float Bs[64][68];
    const int tid = threadIdx.x;
    const int tx = tid & 15, ty = tid >> 4;
    const int bx = blockIdx.x, by = blockIdx.y, gz = blockIdx.z;
    const float* W    = (gz == 0) ? Wq : (gz == 1 ? Wk : Wv);
    const float* bias = (gz == 0) ? bq : (gz == 1 ? bk : bvp);
    float* dst        = (gz == 0) ? qw : (gz == 1 ? kw : vw);

    const int ldc = tx * 4;

    float acc[4][4];
#pragma unroll
    for (int i = 0; i < 4; i++)
#pragma unroll
        for (int j = 0; j < 4; j++) acc[i][j] = 0.f;

    for (int k0 = 0; k0 < EMB; k0 += 64) {
        __syncthreads();
#pragma unroll
        for (int i = 0; i < 4; i++) {
            int r = ty + 16 * i;
            float4 a = *(const float4*)&hs[(size_t)(by * 64 + r) * EMB + k0 + ldc];
            AsT[ldc + 0][r] = a.x; AsT[ldc + 1][r] = a.y;
            AsT[ldc + 2][r] = a.z; AsT[ldc + 3][r] = a.w;
            *(float4*)&Bs[r][ldc] =
                *(const float4*)&W[(size_t)(k0 + r) * EMB + bx * 64 + ldc];
        }
        __syncthreads();
#pragma unroll 8
        for (int kk = 0; kk < 64; kk++) {
            float av[4], bb[4];
            *(float4*)av = *(const float4*)&AsT[kk][ty * 4];
            *(float4*)bb = *(const float4*)&Bs[kk][tx * 4];
#pragma unroll
            for (int i = 0; i < 4; i++)
#pragma unroll
                for (int j = 0; j < 4; j++)
                    acc[i][j] = fmaf(av[i], bb[j], acc[i][j]);
        }
    }

#pragma unroll
    for (int i = 0; i < 4; i++) {
        int m = by * 64 + ty * 4 + i;
        int b2 = m / L_SEQ, l = m % L_SEQ;
        float o[4];
#pragma unroll
        for (int j = 0; j < 4; j++) o[j] = acc[i][j] + bias[bx * 64 + tx * 4 + j];
        *(float4*)&dst[((size_t)(b2 * NH + bx) * L_SEQ + l) * DH + tx * 4] = *(float4*)o;
    }
}

// ---------------------------------------------------------------------------
// K2: softmax partial stats. Block = (bh, 64-q tile, k-quarter of 192).
// 4 waves x 16 q rows; lane = (qr, d); K chunk [64k][64dim] staged in LDS.
// ---------------------------------------------------------------------------
__global__ __launch_bounds__(256) void k2_stats(
    const float* __restrict__ qw, const float* __restrict__ kw,
    const float* __restrict__ mask, float* __restrict__ part)
{
    __shared__ float k_lds[64 * 64];
    __shared__ float m_lds[64];
    const int tid = threadIdx.x;
    const int lane = tid & 63, w = tid >> 6;
    const int qr = lane >> 3, d = lane & 7;
    const int blk = blockIdx.x;
    const int kq = blk & 3;
    const int t2 = blk >> 2;            // 0..287
    const int bh = t2 / 12;
    const int q0 = (t2 % 12) * 64;
    const int b = bh / NH;
    const int qw0 = q0 + w * 16;

    float qf[2][8];
#pragma unroll
    for (int qq = 0; qq < 2; qq++) {
        const float* qp = &qw[((size_t)bh * L_SEQ + qw0 + qr + qq * 8) * DH + d * 8];
        *(float4*)&qf[qq][0] = *(const float4*)qp;
        *(float4*)&qf[qq][4] = *(const float4*)(qp + 4);
    }
    float S[2] = {0.f, 0.f}, T2[2] = {0.f, 0.f}, SL[2] = {0.f, 0.f};
    float M[2] = {-1e30f, -1e30f};

    const int kb0 = kq * 192;
    for (int c = 0; c < 3; c++) {
        const int kb = kb0 + c * 64;
        __syncthreads();
        {
            const float* src = &kw[((size_t)bh * L_SEQ + kb) * DH];
#pragma unroll
            for (int i = 0; i < 4; i++) {
                int f = tid + 256 * i;
                *(float4*)&k_lds[f * 4] = *(const float4*)&src[f * 4];
            }
            if (tid < 64) m_lds[tid] = mask[b * L_SEQ + kb + tid];
        }
        __syncthreads();
#pragma unroll 4
        for (int kk = 0; kk < 64; kk++) {
            float kv[8];
            *(float4*)&kv[0] = *(const float4*)&k_lds[kk * 64 + d * 8];
            *(float4*)&kv[4] = *(const float4*)&k_lds[kk * 64 + d * 8 + 4];
            float mval = m_lds[kk];
#pragma unroll
            for (int qq = 0; qq < 2; qq++) {
                float s = 0.f;
#pragma unroll
                for (int t = 0; t < 8; t++) s = fmaf(qf[qq][t], kv[t], s);
                s = fmaf(s, RSQRT8, mval);
                float e = __expf(s);
                S[qq] += e;
                T2[qq] = fmaf(e, e, T2[qq]);
                SL[qq] = fmaf(s, e, SL[qq]);
                M[qq] = fmaxf(M[qq], s);
            }
        }
    }
#pragma unroll
    for (int qq = 0; qq < 2; qq++) {
        int q = qw0 + qr + qq * 8;
        size_t base = (size_t)(bh * 8 + d) * 16;
        part[(base + 0 + kq) * 768 + q] = S[qq];
        part[(base + 4 + kq) * 768 + q] = T2[qq];
        part[(base + 8 + kq) * 768 + q] = SL[qq];
        part[(base + 12 + kq) * 768 + q] = M[qq];
    }
}

// ---------------------------------------------------------------------------
// K3a: per-(b,d,h) combine of k-quarters -> row stats -> linv + stat sums.
// Stores 1/S in [bh][q][d] layout so k45 fetches all 8 d-values for a q row
// with one uniform (scalar) 8-float load.
// ---------------------------------------------------------------------------
__global__ __launch_bounds__(256) void k3_reduce(
    const float* __restrict__ part, float* __restrict__ linv,
    float* __restrict__ part2)
{
    const int bdh = blockIdx.x;         // ((b*8+d)*12+h)
    const int bd = bdh / 12, h = bdh % 12;
    const int b = bd >> 3, d = bd & 7;
    const int bh = b * NH + h;
    const int tid = threadIdx.x;
    const int lane = tid & 63, wave = tid >> 6;
    const size_t base = (size_t)(bh * 8 + d) * 16;
    float acc[4] = {0.f, 0.f, 0.f, 0.f};

    for (int q = tid; q < 768; q += 256) {
        float Sv = 0.f, T2v = 0.f, SLv = 0.f, Mv = -1e30f;
#pragma unroll
        for (int kq = 0; kq < 4; kq++) {
            Sv  += part[(base + 0 + kq) * 768 + q];
            T2v += part[(base + 4 + kq) * 768 + q];
            SLv += part[(base + 8 + kq) * 768 + q];
            Mv = fmaxf(Mv, part[(base + 12 + kq) * 768 + q]);
        }
        float inv = 1.0f / Sv;
        linv[((size_t)bh * 768 + q) * 8 + d] = inv;
        float hhi = T2v * inv * inv;
        float maxp = __expf(Mv) * inv;
        float ent = __logf(Sv) - SLv * inv;
        float var = (hhi - (1.0f / 768.0f)) * (1.0f / 767.0f);
        acc[0] += var; acc[1] += maxp; acc[2] += ent; acc[3] += hhi;
    }
    __shared__ float red[4][4];
#pragma unroll
    for (int st = 0; st < 4; st++) {
        float a = acc[st];
#pragma unroll
        for (int off = 32; off > 0; off >>= 1) a += __shfl_xor(a, off, 64);
        acc[st] = a;
    }
    if (lane == 0) {
#pragma unroll
        for (int st = 0; st < 4; st++) red[wave][st] = acc[st];
    }
    __syncthreads();
    if (tid == 0) {
#pragma unroll
        for (int st = 0; st < 4; st++)
            part2[(size_t)(bd * 12 + h) * 4 + st] =
                red[0][st] + red[1][st] + red[2][st] + red[3][st];
    }
}

// ---------------------------------------------------------------------------
// K3b: sum over h, min-max norm over d, softmax(2.5*score) -> weights[b][d].
// ---------------------------------------------------------------------------
__global__ __launch_bounds__(64) void k3_weights(
    const float* __restrict__ part2, float* __restrict__ wgt)
{
    __shared__ float stats_l[64];       // [b][d][st]
    const int tid = threadIdx.x;
    {
        const int bd = tid >> 2, st = tid & 3;
        float s = 0.f;
#pragma unroll
        for (int h = 0; h < 12; h++) s += part2[(size_t)(bd * 12 + h) * 4 + st];
        stats_l[tid] = s * (1.0f / 9216.0f);
    }
    __syncthreads();
    if (tid == 0) {
        for (int b = 0; b < BATCH; b++) {
            float v[4][8];
            for (int st = 0; st < 4; st++)
                for (int d = 0; d < 8; d++) v[st][d] = stats_l[(b * 8 + d) * 4 + st];
            float nrm[4][8];
            for (int st = 0; st < 4; st++) {
                float mn = v[st][0], mx = v[st][0];
                for (int d = 1; d < 8; d++) { mn = fminf(mn, v[st][d]); mx = fmaxf(mx, v[st][d]); }
                float rng = fmaxf(mx - mn, 1e-12f);
                for (int d = 0; d < 8; d++) nrm[st][d] = (v[st][d] - mn) / rng;
            }
            float sc[8];
            for (int d = 0; d < 8; d++)
                sc[d] = 0.5f * nrm[0][d] + 0.3f * nrm[1][d] + 0.2f * nrm[3][d] - 0.4f * nrm[2][d];
            float m = 2.5f * sc[0];
            for (int d = 1; d < 8; d++) m = fmaxf(m, 2.5f * sc[d]);
            float e8[8]; float ssum = 0.f;
            for (int d = 0; d < 8; d++) { e8[d] = __expf(2.5f * sc[d] - m); ssum += e8[d]; }
            for (int d = 0; d < 8; d++) wgt[b * ND + d] = e8[d] / ssum;
        }
    }
}

// ---------------------------------------------------------------------------
// K45 v5 (round-12): pipe-split a4+ctx with FIXED occupancy geometry.
// ROUND-11 LESSON (rocprof): v4's pipe-split worked (bank conflicts 30x down,
// VGPR 88) but ran at 14% occupancy (grid 576 = 2.25 blk/CU, LDS 36.9KB):
// ~1-2 waves/SIMD left the phase-A scalar-load -> dot -> exp chains exposed
// (VALUBusy 35%, 156us). The pipe split is right; the parallelism was not.
// v5: SAME structure, occupancy tripled:
//   - grid 1152 (16-q-row blocks): 4.5 blocks/CU.
//   - LDS 20.5KB (a4T [64][20] per wave; ctx-reduce region reuses it).
//   - __launch_bounds__(256,4): VGPR capped 128 (kv 64 + acc 16 + misc fits)
//     -> 4 waves/SIMD resident.
//   Q -> uniform (scalar) loads; K -> 64 VGPR per lane; a4T -> LDS (only
//   DS use); V -> per-k VMEM b128 broadcast. Waves partition k (3 chunks of
//   64 each); one barrier; cross-wave ctx reduce. FP order identical to v4.
// ---------------------------------------------------------------------------
__global__ __launch_bounds__(256, 4) void k45_fused(
    const float* __restrict__ qw, const float* __restrict__ kw,
    const float* __restrict__ vw, const float* __restrict__ mask,
    const float* __restrict__ linv, const float* __restrict__ wgt,
    float* __restrict__ out_a4, float* __restrict__ out_ctx)
{
    // per-wave region: a4T [k 64][20 pad] during chunks; ctx [q 16][68 pad] at end
    __shared__ float smem[4][64 * 20];
    const int tid = threadIdx.x;
    const int lane = tid & 63, w = tid >> 6;
    const int blk = blockIdx.x;
    const int bh = blk / 48;                // 0..23
    const int q0 = (blk % 48) * 16;
    const int b = bh / NH, h = bh % NH;
    // phase-B lane mapping: 4 q rows (qg*4..+3) x 4 dh cols (dhl*4..+3)
    const int qg = lane >> 4;               // 0..3
    const int dhl = lane & 15;              // 0..15

    const float* kbase = &kw[(size_t)bh * L_SEQ * DH];
    const float* vbase = &vw[(size_t)bh * L_SEQ * DH];
    const float* qtile = &qw[((size_t)bh * L_SEQ + q0) * DH];   // block-uniform rows
    const float* ltile = &linv[((size_t)bh * L_SEQ + q0) * 8];

    // wgt[b][0..7]: broadcast into VGPRs (v_mul with scalar linv later)
    float wv[8];
#pragma unroll
    for (int d = 0; d < 8; d++) wv[d] = wgt[b * ND + d];

    float acc[4][4];                        // ctx partial: 4 q rows x 4 dh
#pragma unroll
    for (int i = 0; i < 4; i++)
#pragma unroll
        for (int j = 0; j < 4; j++) acc[i][j] = 0.f;

    float* sm = &smem[w][0];

    for (int c = 0; c < 3; c++) {
        const int kb = (w * 3 + c) * 64;    // this wave's k chunk
        const int krow = kb + lane;

        // K row -> VGPRs
        float kv[64];
        {
            const float* kp = &kbase[(size_t)krow * DH];
#pragma unroll
            for (int t = 0; t < 16; t++)
                *(float4*)&kv[t * 4] = *(const float4*)&kp[t * 4];
        }
        const float mval = mask[b * L_SEQ + krow];

        // ---- Phase A: a4(q, krow) for 16 q rows; Q via uniform loads ----
        for (int q4 = 0; q4 < 4; q4++) {
            float a4q[4];
#pragma unroll
            for (int u = 0; u < 4; u++) {
                const int q = q4 * 4 + u;
                const float* qp = &qtile[(size_t)q * DH];
                const float* lp = &ltile[(size_t)q * 8];
                float sd[8];
#pragma unroll
                for (int d = 0; d < 8; d++) sd[d] = 0.f;
#pragma unroll
                for (int d = 0; d < 8; d++)
#pragma unroll
                    for (int t = 0; t < 8; t++)
                        sd[d] = fmaf(qp[d * 8 + t], kv[d * 8 + t], sd[d]);
                float a4v = 0.f;
#pragma unroll
                for (int d = 0; d < 8; d++) {
                    float sv = fmaf(sd[d], RSQRT8, mval);
                    a4v = fmaf(wv[d] * lp[d], __expf(sv), a4v);
                }
                out_a4[((size_t)bh * L_SEQ + q0 + q) * L_SEQ + krow] = a4v;
                a4q[u] = a4v;
            }
            // a4T[k][q4*4..+3] (wave-private; same-wave lgkmcnt ordering)
            *(float4*)&sm[lane * 20 + q4 * 4] = *(float4*)a4q;
        }

        // ---- Phase B: ctx += a4T @ V over this chunk (k ascending) ----
        const float* vrow = &vbase[(size_t)kb * DH + dhl * 4];
#pragma unroll 8
        for (int k = 0; k < 64; k++) {
            float av[4];
            *(float4*)av = *(const float4*)&sm[k * 20 + qg * 4];
            float4 vv = *(const float4*)&vrow[(size_t)k * DH];
#pragma unroll
            for (int i = 0; i < 4; i++) {
                acc[i][0] = fmaf(av[i], vv.x, acc[i][0]);
                acc[i][1] = fmaf(av[i], vv.y, acc[i][1]);
                acc[i][2] = fmaf(av[i], vv.z, acc[i][2]);
                acc[i][3] = fmaf(av[i], vv.w, acc[i][3]);
            }
        }
    }

    // ---- ctx k-partials -> LDS (alias a4T region), block-reduce over waves ----
#pragma unroll
    for (int i = 0; i < 4; i++)
        *(float4*)&sm[(qg * 4 + i) * 68 + dhl * 4] = *(float4*)&acc[i][0];
    __syncthreads();
    {
        const int q = tid >> 4;             // 0..15
        const int dh4 = (tid & 15) * 4;     // 0..60
        float r[4] = {0.f, 0.f, 0.f, 0.f};
#pragma unroll
        for (int ww = 0; ww < 4; ww++) {
            const float* s2 = &smem[ww][q * 68 + dh4];
#pragma unroll
            for (int j = 0; j < 4; j++) r[j] += s2[j];
        }
        *(float4*)&out_ctx[((size_t)b * L_SEQ + q0 + q) * EMB + h * DH + dh4] =
            *(float4*)r;
    }
}

// ---------------------------------------------------------------------------
extern "C" void kernel_launch(void* const* d_in, const int* in_sizes, int n_in,
                              void* d_out, int out_size, void* d_ws, size_t ws_size,
                              hipStream_t stream)
{
    const float* hs   = (const float*)d_in[0];
    const float* mask = (const float*)d_in[1];
    const float* Wq   = (const float*)d_in[2];
    const float* bq   = (const float*)d_in[3];
    const float* Wk   = (const float*)d_in[4];
    const float* bk   = (const float*)d_in[5];
    const float* Wv   = (const float*)d_in[6];
    const float* bv   = (const float*)d_in[7];

    float* ws = (float*)d_ws;
    float* qw    = ws + OFF_Q;
    float* kw    = ws + OFF_K;
    float* vw    = ws + OFF_V;
    float* linv  = ws + OFF_L;
    float* part  = ws + OFF_PART;
    float* part2 = ws + OFF_P2;
    float* wgt   = ws + OFF_W;

    float* out_ctx = (float*)d_out;                                  // [B, L, 768]
    float* out_a4  = (float*)d_out + (size_t)BATCH * L_SEQ * EMB;    // [B, H, L, L]

    k1_qkv<<<dim3(12, 24, 3), 256, 0, stream>>>(hs, Wq, bq, Wk, bk, Wv, bv, qw, kw, vw);
    k2_stats<<<dim3(1152), 256, 0, stream>>>(qw, kw, mask, part);
    k3_reduce<<<dim3(192), 256, 0, stream>>>(part, linv, part2);
    k3_weights<<<dim3(1), 64, 0, stream>>>(part2, wgt);
    k45_fused<<<dim3(1152), 256, 0, stream>>>(qw, kw, vw, mask, linv, wgt,
                                              out_a4, out_ctx);
}

// Round 6
// 317.323 us; speedup vs baseline: 2.8790x; 1.0413x over previous
//
#include <hip/hip_runtime.h>

// Problem constants (fixed by reference setup_inputs)
#define BATCH 2
#define L_SEQ 768
#define NH 12
#define DH 64
#define ND 8
#define EMB 768
#define RSQRT8 0.35355339059327373f

// ws layout (floats). Total 6,046,480 floats = 24.2 MB -- UNCHANGED footprint.
#define OFF_Q    0
#define OFF_K    1179648
#define OFF_V    2359296
#define OFF_L    3538944   // linv[bh][q][d] = 1/S : 147456
#define OFF_PART 3686400   // partial stats [bh*8+d][st*4+kq][q]: 2359296
#define OFF_P2   6045696   // per-(b,d,h) stat sums [bd][h][st]: 768
#define OFF_W    6046464   // weights [b][d]: 16

// ---------------------------------------------------------------------------
// K1: fused QKV projection. C = hs @ W + b, scattered to [b][h][l][64] layout.
// 64x64 tiles, 4x4 per thread, fp32 (no fp32 MFMA on CDNA4).
// ---------------------------------------------------------------------------
__global__ __launch_bounds__(256) void k1_qkv(
    const float* __restrict__ hs,
    const float* __restrict__ Wq, const float* __restrict__ bq,
    const float* __restrict__ Wk, const float* __restrict__ bk,
    const float* __restrict__ Wv, const float* __restrict__ bvp,
    float* __restrict__ qw, float* __restrict__ kw, float* __restrict__ vw)
{
    __shared__ float AsT[64][68];
    __shared__ float Bs[64][68];
    const int tid = threadIdx.x;
    const int tx = tid & 15, ty = tid >> 4;
    const int bx = blockIdx.x, by = blockIdx.y, gz = blockIdx.z;
    const float* W    = (gz == 0) ? Wq : (gz == 1 ? Wk : Wv);
    const float* bias = (gz == 0) ? bq : (gz == 1 ? bk : bvp);
    float* dst        = (gz == 0) ? qw : (gz == 1 ? kw : vw);

    const int ldc = tx * 4;

    float acc[4][4];
#pragma unroll
    for (int i = 0; i < 4; i++)
#pragma unroll
        for (int j = 0; j < 4; j++) acc[i][j] = 0.f;

    for (int k0 = 0; k0 < EMB; k0 += 64) {
        __syncthreads();
#pragma unroll
        for (int i = 0; i < 4; i++) {
            int r = ty + 16 * i;
            float4 a = *(const float4*)&hs[(size_t)(by * 64 + r) * EMB + k0 + ldc];
            AsT[ldc + 0][r] = a.x; AsT[ldc + 1][r] = a.y;
            AsT[ldc + 2][r] = a.z; AsT[ldc + 3][r] = a.w;
            *(float4*)&Bs[r][ldc] =
                *(const float4*)&W[(size_t)(k0 + r) * EMB + bx * 64 + ldc];
        }
        __syncthreads();
#pragma unroll 8
        for (int kk = 0; kk < 64; kk++) {
            float av[4], bb[4];
            *(float4*)av = *(const float4*)&AsT[kk][ty * 4];
            *(float4*)bb = *(const float4*)&Bs[kk][tx * 4];
#pragma unroll
            for (int i = 0; i < 4; i++)
#pragma unroll
                for (int j = 0; j < 4; j++)
                    acc[i][j] = fmaf(av[i], bb[j], acc[i][j]);
        }
    }

#pragma unroll
    for (int i = 0; i < 4; i++) {
        int m = by * 64 + ty * 4 + i;
        int b2 = m / L_SEQ, l = m % L_SEQ;
        float o[4];
#pragma unroll
        for (int j = 0; j < 4; j++) o[j] = acc[i][j] + bias[bx * 64 + tx * 4 + j];
        *(float4*)&dst[((size_t)(b2 * NH + bx) * L_SEQ + l) * DH + tx * 4] = *(float4*)o;
    }
}

// ---------------------------------------------------------------------------
// K2: softmax partial stats. Block = (bh, 64-q tile, k-quarter of 192).
// 4 waves x 16 q rows; lane = (qr, d); K chunk [64k][64dim] staged in LDS.
// Round-13: XCD-chunked bijective swizzle (1152 % 8 == 0) so the 48 blocks of
// one bh co-locate on one XCD -> K slab L2-resident.
// ---------------------------------------------------------------------------
__global__ __launch_bounds__(256) void k2_stats(
    const float* __restrict__ qw, const float* __restrict__ kw,
    const float* __restrict__ mask, float* __restrict__ part)
{
    __shared__ float k_lds[64 * 64];
    __shared__ float m_lds[64];
    const int tid = threadIdx.x;
    const int lane = tid & 63, w = tid >> 6;
    const int qr = lane >> 3, d = lane & 7;
    const int lb = (blockIdx.x & 7) * 144 + (blockIdx.x >> 3);
    const int kq = lb & 3;
    const int t2 = lb >> 2;             // 0..287
    const int bh = t2 / 12;
    const int q0 = (t2 % 12) * 64;
    const int b = bh / NH;
    const int qw0 = q0 + w * 16;

    float qf[2][8];
#pragma unroll
    for (int qq = 0; qq < 2; qq++) {
        const float* qp = &qw[((size_t)bh * L_SEQ + qw0 + qr + qq * 8) * DH + d * 8];
        *(float4*)&qf[qq][0] = *(const float4*)qp;
        *(float4*)&qf[qq][4] = *(const float4*)(qp + 4);
    }
    float S[2] = {0.f, 0.f}, T2[2] = {0.f, 0.f}, SL[2] = {0.f, 0.f};
    float M[2] = {-1e30f, -1e30f};

    const int kb0 = kq * 192;
    for (int c = 0; c < 3; c++) {
        const int kb = kb0 + c * 64;
        __syncthreads();
        {
            const float* src = &kw[((size_t)bh * L_SEQ + kb) * DH];
#pragma unroll
            for (int i = 0; i < 4; i++) {
                int f = tid + 256 * i;
                *(float4*)&k_lds[f * 4] = *(const float4*)&src[f * 4];
            }
            if (tid < 64) m_lds[tid] = mask[b * L_SEQ + kb + tid];
        }
        __syncthreads();
#pragma unroll 4
        for (int kk = 0; kk < 64; kk++) {
            float kv[8];
            *(float4*)&kv[0] = *(const float4*)&k_lds[kk * 64 + d * 8];
            *(float4*)&kv[4] = *(const float4*)&k_lds[kk * 64 + d * 8 + 4];
            float mval = m_lds[kk];
#pragma unroll
            for (int qq = 0; qq < 2; qq++) {
                float s = 0.f;
#pragma unroll
                for (int t = 0; t < 8; t++) s = fmaf(qf[qq][t], kv[t], s);
                s = fmaf(s, RSQRT8, mval);
                float e = __expf(s);
                S[qq] += e;
                T2[qq] = fmaf(e, e, T2[qq]);
                SL[qq] = fmaf(s, e, SL[qq]);
                M[qq] = fmaxf(M[qq], s);
            }
        }
    }
#pragma unroll
    for (int qq = 0; qq < 2; qq++) {
        int q = qw0 + qr + qq * 8;
        size_t base = (size_t)(bh * 8 + d) * 16;
        part[(base + 0 + kq) * 768 + q] = S[qq];
        part[(base + 4 + kq) * 768 + q] = T2[qq];
        part[(base + 8 + kq) * 768 + q] = SL[qq];
        part[(base + 12 + kq) * 768 + q] = M[qq];
    }
}

// ---------------------------------------------------------------------------
// K3a: per-(b,d,h) combine of k-quarters -> row stats -> linv + stat sums.
// Stores 1/S in [bh][q][d] layout so k45 fetches all 8 d-values for a q row
// with one uniform (scalar) 8-float load.
// ---------------------------------------------------------------------------
__global__ __launch_bounds__(256) void k3_reduce(
    const float* __restrict__ part, float* __restrict__ linv,
    float* __restrict__ part2)
{
    const int bdh = blockIdx.x;         // ((b*8+d)*12+h)
    const int bd = bdh / 12, h = bdh % 12;
    const int b = bd >> 3, d = bd & 7;
    const int bh = b * NH + h;
    const int tid = threadIdx.x;
    const int lane = tid & 63, wave = tid >> 6;
    const size_t base = (size_t)(bh * 8 + d) * 16;
    float acc[4] = {0.f, 0.f, 0.f, 0.f};

    for (int q = tid; q < 768; q += 256) {
        float Sv = 0.f, T2v = 0.f, SLv = 0.f, Mv = -1e30f;
#pragma unroll
        for (int kq = 0; kq < 4; kq++) {
            Sv  += part[(base + 0 + kq) * 768 + q];
            T2v += part[(base + 4 + kq) * 768 + q];
            SLv += part[(base + 8 + kq) * 768 + q];
            Mv = fmaxf(Mv, part[(base + 12 + kq) * 768 + q]);
        }
        float inv = 1.0f / Sv;
        linv[((size_t)bh * 768 + q) * 8 + d] = inv;
        float hhi = T2v * inv * inv;
        float maxp = __expf(Mv) * inv;
        float ent = __logf(Sv) - SLv * inv;
        float var = (hhi - (1.0f / 768.0f)) * (1.0f / 767.0f);
        acc[0] += var; acc[1] += maxp; acc[2] += ent; acc[3] += hhi;
    }
    __shared__ float red[4][4];
#pragma unroll
    for (int st = 0; st < 4; st++) {
        float a = acc[st];
#pragma unroll
        for (int off = 32; off > 0; off >>= 1) a += __shfl_xor(a, off, 64);
        acc[st] = a;
    }
    if (lane == 0) {
#pragma unroll
        for (int st = 0; st < 4; st++) red[wave][st] = acc[st];
    }
    __syncthreads();
    if (tid == 0) {
#pragma unroll
        for (int st = 0; st < 4; st++)
            part2[(size_t)(bd * 12 + h) * 4 + st] =
                red[0][st] + red[1][st] + red[2][st] + red[3][st];
    }
}

// ---------------------------------------------------------------------------
// K3b: sum over h, min-max norm over d, softmax(2.5*score) -> weights[b][d].
// ---------------------------------------------------------------------------
__global__ __launch_bounds__(64) void k3_weights(
    const float* __restrict__ part2, float* __restrict__ wgt)
{
    __shared__ float stats_l[64];       // [b][d][st]
    const int tid = threadIdx.x;
    {
        const int bd = tid >> 2, st = tid & 3;
        float s = 0.f;
#pragma unroll
        for (int h = 0; h < 12; h++) s += part2[(size_t)(bd * 12 + h) * 4 + st];
        stats_l[tid] = s * (1.0f / 9216.0f);
    }
    __syncthreads();
    if (tid == 0) {
        for (int b = 0; b < BATCH; b++) {
            float v[4][8];
            for (int st = 0; st < 4; st++)
                for (int d = 0; d < 8; d++) v[st][d] = stats_l[(b * 8 + d) * 4 + st];
            float nrm[4][8];
            for (int st = 0; st < 4; st++) {
                float mn = v[st][0], mx = v[st][0];
                for (int d = 1; d < 8; d++) { mn = fminf(mn, v[st][d]); mx = fmaxf(mx, v[st][d]); }
                float rng = fmaxf(mx - mn, 1e-12f);
                for (int d = 0; d < 8; d++) nrm[st][d] = (v[st][d] - mn) / rng;
            }
            float sc[8];
            for (int d = 0; d < 8; d++)
                sc[d] = 0.5f * nrm[0][d] + 0.3f * nrm[1][d] + 0.2f * nrm[3][d] - 0.4f * nrm[2][d];
            float m = 2.5f * sc[0];
            for (int d = 1; d < 8; d++) m = fmaxf(m, 2.5f * sc[d]);
            float e8[8]; float ssum = 0.f;
            for (int d = 0; d < 8; d++) { e8[d] = __expf(2.5f * sc[d] - m); ssum += e8[d]; }
            for (int d = 0; d < 8; d++) wgt[b * ND + d] = e8[d] / ssum;
        }
    }
}

// ---------------------------------------------------------------------------
// K45 v6 (round-13): pipe-split a4+ctx with REGISTER-RESIDENT K.
// ROUND-12 LESSON (rocprof): v5's VGPR_Count=56 < kv[64] PROVED the compiler
// was reloading K from global inside the q loop (4-wide q unroll pushed live
// pressure past the 128 cap of launch_bounds(256,4)): FETCH 50MB, VALUBusy
// 50%, 111us. Two fixes:
//   1. Phase A = ONE q at a time (#pragma unroll 2): live set = kv 64 +
//      2x sd 8 + misc ~ 100 < 128 -> kv stays resident, phase A steady state
//      is pure VALU/SALU (Q via s_load). a4T store becomes scalar ds_write
//      (DS pipe idle anyway). Per-(q,k) FP order identical to v5.
//   2. XCD-chunked bijective swizzle (1152 = 8 x 144): the 48 q-tile blocks
//      of one bh co-locate per XCD -> K/V/Q slabs (1.7MB per 3 bh) become
//      L2-resident instead of cross-XCD L3 re-fetches.
// Verification signals: VGPR >= 64 (kv resident), FETCH ~15-20MB (no reloads
// + L2 locality), VALUBusy >= 65%.
// ---------------------------------------------------------------------------
__global__ __launch_bounds__(256, 4) void k45_fused(
    const float* __restrict__ qw, const float* __restrict__ kw,
    const float* __restrict__ vw, const float* __restrict__ mask,
    const float* __restrict__ linv, const float* __restrict__ wgt,
    float* __restrict__ out_a4, float* __restrict__ out_ctx)
{
    // per-wave region: a4T [k 64][20 pad] during chunks; ctx [q 16][68 pad] at end
    __shared__ float smem[4][64 * 20];
    const int tid = threadIdx.x;
    const int lane = tid & 63, w = tid >> 6;
    // XCD-chunked bijective swizzle: logical blocks 0..143 -> XCD0, etc.
    const int lb = (blockIdx.x & 7) * 144 + (blockIdx.x >> 3);
    const int bh = lb / 48;                 // 0..23
    const int q0 = (lb % 48) * 16;
    const int b = bh / NH, h = bh % NH;
    // phase-B lane mapping: 4 q rows (qg*4..+3) x 4 dh cols (dhl*4..+3)
    const int qg = lane >> 4;               // 0..3
    const int dhl = lane & 15;              // 0..15

    const float* kbase = &kw[(size_t)bh * L_SEQ * DH];
    const float* vbase = &vw[(size_t)bh * L_SEQ * DH];
    const float* qtile = &qw[((size_t)bh * L_SEQ + q0) * DH];   // block-uniform rows
    const float* ltile = &linv[((size_t)bh * L_SEQ + q0) * 8];

    // wgt[b][0..7]: broadcast
    float wv[8];
#pragma unroll
    for (int d = 0; d < 8; d++) wv[d] = wgt[b * ND + d];

    float acc[4][4];                        // ctx partial: 4 q rows x 4 dh
#pragma unroll
    for (int i = 0; i < 4; i++)
#pragma unroll
        for (int j = 0; j < 4; j++) acc[i][j] = 0.f;

    float* sm = &smem[w][0];

    for (int c = 0; c < 3; c++) {
        const int kb = (w * 3 + c) * 64;    // this wave's k chunk
        const int krow = kb + lane;

        // K row -> VGPRs (must stay resident: see header comment)
        float kv[64];
        {
            const float* kp = &kbase[(size_t)krow * DH];
#pragma unroll
            for (int t = 0; t < 16; t++)
                *(float4*)&kv[t * 4] = *(const float4*)&kp[t * 4];
        }
        const float mval = mask[b * L_SEQ + krow];

        // ---- Phase A: a4(q, krow), one q at a time, K register-resident ----
#pragma unroll 2
        for (int q = 0; q < 16; q++) {
            const float* qp = &qtile[(size_t)q * DH];
            const float* lp = &ltile[(size_t)q * 8];
            float sd[8];
#pragma unroll
            for (int d = 0; d < 8; d++) sd[d] = 0.f;
#pragma unroll
            for (int d = 0; d < 8; d++)
#pragma unroll
                for (int t = 0; t < 8; t++)
                    sd[d] = fmaf(qp[d * 8 + t], kv[d * 8 + t], sd[d]);
            float a4v = 0.f;
#pragma unroll
            for (int d = 0; d < 8; d++) {
                float sv = fmaf(sd[d], RSQRT8, mval);
                a4v = fmaf(wv[d] * lp[d], __expf(sv), a4v);
            }
            out_a4[((size_t)bh * L_SEQ + q0 + q) * L_SEQ + krow] = a4v;
            sm[lane * 20 + q] = a4v;        // a4T[k][q] (wave-private)
        }

        // ---- Phase B: ctx += a4T @ V over this chunk (k ascending) ----
        const float* vrow = &vbase[(size_t)kb * DH + dhl * 4];
#pragma unroll 8
        for (int k = 0; k < 64; k++) {
            float av[4];
            *(float4*)av = *(const float4*)&sm[k * 20 + qg * 4];
            float4 vv = *(const float4*)&vrow[(size_t)k * DH];
#pragma unroll
            for (int i = 0; i < 4; i++) {
                acc[i][0] = fmaf(av[i], vv.x, acc[i][0]);
                acc[i][1] = fmaf(av[i], vv.y, acc[i][1]);
                acc[i][2] = fmaf(av[i], vv.z, acc[i][2]);
                acc[i][3] = fmaf(av[i], vv.w, acc[i][3]);
            }
        }
    }

    // ---- ctx k-partials -> LDS (alias a4T region), block-reduce over waves ----
#pragma unroll
    for (int i = 0; i < 4; i++)
        *(float4*)&sm[(qg * 4 + i) * 68 + dhl * 4] = *(float4*)&acc[i][0];
    __syncthreads();
    {
        const int q = tid >> 4;             // 0..15
        const int dh4 = (tid & 15) * 4;     // 0..60
        float r[4] = {0.f, 0.f, 0.f, 0.f};
#pragma unroll
        for (int ww = 0; ww < 4; ww++) {
            const float* s2 = &smem[ww][q * 68 + dh4];
#pragma unroll
            for (int j = 0; j < 4; j++) r[j] += s2[j];
        }
        *(float4*)&out_ctx[((size_t)b * L_SEQ + q0 + q) * EMB + h * DH + dh4] =
            *(float4*)r;
    }
}

// ---------------------------------------------------------------------------
extern "C" void kernel_launch(void* const* d_in, const int* in_sizes, int n_in,
                              void* d_out, int out_size, void* d_ws, size_t ws_size,
                              hipStream_t stream)
{
    const float* hs   = (const float*)d_in[0];
    const float* mask = (const float*)d_in[1];
    const float* Wq   = (const float*)d_in[2];
    const float* bq   = (const float*)d_in[3];
    const float* Wk   = (const float*)d_in[4];
    const float* bk   = (const float*)d_in[5];
    const float* Wv   = (const float*)d_in[6];
    const float* bv   = (const float*)d_in[7];

    float* ws = (float*)d_ws;
    float* qw    = ws + OFF_Q;
    float* kw    = ws + OFF_K;
    float* vw    = ws + OFF_V;
    float* linv  = ws + OFF_L;
    float* part  = ws + OFF_PART;
    float* part2 = ws + OFF_P2;
    float* wgt   = ws + OFF_W;

    float* out_ctx = (float*)d_out;                                  // [B, L, 768]
    float* out_a4  = (float*)d_out + (size_t)BATCH * L_SEQ * EMB;    // [B, H, L, L]

    k1_qkv<<<dim3(12, 24, 3), 256, 0, stream>>>(hs, Wq, bq, Wk, bk, Wv, bv, qw, kw, vw);
    k2_stats<<<dim3(1152), 256, 0, stream>>>(qw, kw, mask, part);
    k3_reduce<<<dim3(192), 256, 0, stream>>>(part, linv, part2);
    k3_weights<<<dim3(1), 64, 0, stream>>>(part2, wgt);
    k45_fused<<<dim3(1152), 256, 0, stream>>>(qw, kw, vw, mask, linv, wgt,
                                              out_a4, out_ctx);
}